// Round 1
// baseline (10216.380 us; speedup 1.0000x reference)
//
#include <hip/hip_runtime.h>
#include <math.h>

#define N_NODES 100000
#define N_EDGES 1600000
#define HID 128
#define VOCAB 1000
#define ROWSTR 1000   // floats per output row (also per-node scratch slot)

// per-node scratch layout inside its own d_out row
#define OFF_H   0
#define OFF_AGG 128
#define OFF_CNT 256

#define TNB 8   // nodes per transform block
#define FNB 4   // nodes per final block

// h[i] = emb[x[i]], agg = 0, cnt = 0
__global__ __launch_bounds__(HID) void k_embed(float* __restrict__ base,
                                               const int* __restrict__ x,
                                               const float* __restrict__ emb) {
    int i = blockIdx.x;
    int j = threadIdx.x;
    float* row = base + (size_t)i * ROWSTR;
    row[OFF_H + j] = emb[x[i] * HID + j];
    row[OFF_AGG + j] = 0.f;
    if (j == 0) row[OFF_CNT] = 0.f;
}

// agg[dst] += h[src] ; cnt[dst] += 1     (32 threads per edge, 4 ch each)
__global__ __launch_bounds__(256) void k_scatter(float* __restrict__ base,
                                                 const int* __restrict__ src,
                                                 const int* __restrict__ dst) {
    long long gid = (long long)blockIdx.x * blockDim.x + threadIdx.x;
    int e = (int)(gid >> 5);
    if (e >= N_EDGES) return;
    int l = (int)(gid & 31);
    int s = src[e];
    int d = dst[e];
    const float4 v = *(const float4*)(base + (size_t)s * ROWSTR + OFF_H + l * 4);
    float* ad = base + (size_t)d * ROWSTR + OFF_AGG + l * 4;
    atomicAdd(ad + 0, v.x);
    atomicAdd(ad + 1, v.y);
    atomicAdd(ad + 2, v.z);
    atomicAdd(ad + 3, v.w);
    if (l == 0) atomicAdd(base + (size_t)d * ROWSTR + OFF_CNT, 1.0f);
}

// h = relu(mean @ Wl + bl + h @ Wr), in place; re-zero agg/cnt for next layer
__global__ __launch_bounds__(HID) void k_transform(float* __restrict__ base,
                                                   const float* __restrict__ Wl,
                                                   const float* __restrict__ bl,
                                                   const float* __restrict__ Wr) {
    int j = threadIdx.x;
    int i0 = blockIdx.x * TNB;
    __shared__ __align__(16) float s_m[TNB][HID];
    __shared__ __align__(16) float s_h[TNB][HID];

    #pragma unroll
    for (int r = 0; r < TNB; ++r) {
        const float* row = base + (size_t)(i0 + r) * ROWSTR;
        float c = fmaxf(row[OFF_CNT], 1.0f);
        s_m[r][j] = row[OFF_AGG + j] / c;
        s_h[r][j] = row[OFF_H + j];
    }
    __syncthreads();

    float acc[TNB];
    #pragma unroll
    for (int r = 0; r < TNB; ++r) acc[r] = 0.f;

    for (int k4 = 0; k4 < HID / 4; ++k4) {
        int k = 4 * k4;
        float wl0 = Wl[(k + 0) * HID + j];
        float wl1 = Wl[(k + 1) * HID + j];
        float wl2 = Wl[(k + 2) * HID + j];
        float wl3 = Wl[(k + 3) * HID + j];
        float wr0 = Wr[(k + 0) * HID + j];
        float wr1 = Wr[(k + 1) * HID + j];
        float wr2 = Wr[(k + 2) * HID + j];
        float wr3 = Wr[(k + 3) * HID + j];
        #pragma unroll
        for (int r = 0; r < TNB; ++r) {
            float4 mv = ((const float4*)s_m[r])[k4];
            float4 hv = ((const float4*)s_h[r])[k4];
            acc[r] += mv.x * wl0 + mv.y * wl1 + mv.z * wl2 + mv.w * wl3
                    + hv.x * wr0 + hv.y * wr1 + hv.z * wr2 + hv.w * wr3;
        }
    }

    float bb = bl[j];
    #pragma unroll
    for (int r = 0; r < TNB; ++r) {
        float* row = base + (size_t)(i0 + r) * ROWSTR;
        row[OFF_H + j] = fmaxf(acc[r] + bb, 0.f);
        row[OFF_AGG + j] = 0.f;
        if (j == 0) row[OFF_CNT] = 0.f;
    }
}

// out[i] = softmax(h[i] @ Wlast + blast), overwriting the scratch rows
__global__ __launch_bounds__(256) void k_final(float* __restrict__ base,
                                               const float* __restrict__ Wlast,
                                               const float* __restrict__ blast) {
    int t = threadIdx.x;
    int i0 = blockIdx.x * FNB;
    __shared__ __align__(16) float sh[FNB][HID];
    __shared__ float sred[FNB * 4];

    for (int u = t; u < FNB * HID; u += 256) {
        int r = u >> 7, k = u & 127;
        sh[r][k] = base[(size_t)(i0 + r) * ROWSTR + OFF_H + k];
    }
    __syncthreads();

    const bool act = (t < 250);
    float acc[FNB][4];
    #pragma unroll
    for (int r = 0; r < FNB; ++r)
        #pragma unroll
        for (int c = 0; c < 4; ++c) acc[r][c] = 0.f;

    if (act) {
        const float4* wp = (const float4*)Wlast + t;  // row k: wp[k*250]
        for (int k4 = 0; k4 < HID / 4; ++k4) {
            int k = 4 * k4;
            float4 w0 = wp[(k + 0) * 250];
            float4 w1 = wp[(k + 1) * 250];
            float4 w2 = wp[(k + 2) * 250];
            float4 w3 = wp[(k + 3) * 250];
            #pragma unroll
            for (int r = 0; r < FNB; ++r) {
                float4 hv = ((const float4*)sh[r])[k4];
                acc[r][0] += hv.x * w0.x + hv.y * w1.x + hv.z * w2.x + hv.w * w3.x;
                acc[r][1] += hv.x * w0.y + hv.y * w1.y + hv.z * w2.y + hv.w * w3.y;
                acc[r][2] += hv.x * w0.z + hv.y * w1.z + hv.z * w2.z + hv.w * w3.z;
                acc[r][3] += hv.x * w0.w + hv.y * w1.w + hv.z * w2.w + hv.w * w3.w;
            }
        }
        float4 bb = ((const float4*)blast)[t];
        #pragma unroll
        for (int r = 0; r < FNB; ++r) {
            acc[r][0] += bb.x; acc[r][1] += bb.y; acc[r][2] += bb.z; acc[r][3] += bb.w;
        }
    }

    // --- block max per node ---
    float lm[FNB];
    #pragma unroll
    for (int r = 0; r < FNB; ++r)
        lm[r] = act ? fmaxf(fmaxf(acc[r][0], acc[r][1]), fmaxf(acc[r][2], acc[r][3]))
                    : -INFINITY;
    #pragma unroll
    for (int s = 32; s > 0; s >>= 1)
        #pragma unroll
        for (int r = 0; r < FNB; ++r)
            lm[r] = fmaxf(lm[r], __shfl_xor(lm[r], s, 64));
    int wave = t >> 6, lane = t & 63;
    if (lane == 0) {
        #pragma unroll
        for (int r = 0; r < FNB; ++r) sred[r * 4 + wave] = lm[r];
    }
    __syncthreads();
    float M[FNB];
    #pragma unroll
    for (int r = 0; r < FNB; ++r)
        M[r] = fmaxf(fmaxf(sred[r * 4 + 0], sred[r * 4 + 1]),
                     fmaxf(sred[r * 4 + 2], sred[r * 4 + 3]));
    __syncthreads();

    // --- exp + block sum per node ---
    float ls[FNB];
    #pragma unroll
    for (int r = 0; r < FNB; ++r) {
        if (act) {
            acc[r][0] = expf(acc[r][0] - M[r]);
            acc[r][1] = expf(acc[r][1] - M[r]);
            acc[r][2] = expf(acc[r][2] - M[r]);
            acc[r][3] = expf(acc[r][3] - M[r]);
            ls[r] = (acc[r][0] + acc[r][1]) + (acc[r][2] + acc[r][3]);
        } else {
            ls[r] = 0.f;
        }
    }
    #pragma unroll
    for (int s = 32; s > 0; s >>= 1)
        #pragma unroll
        for (int r = 0; r < FNB; ++r)
            ls[r] += __shfl_xor(ls[r], s, 64);
    if (lane == 0) {
        #pragma unroll
        for (int r = 0; r < FNB; ++r) sred[r * 4 + wave] = ls[r];
    }
    __syncthreads();

    #pragma unroll
    for (int r = 0; r < FNB; ++r) {
        float S = (sred[r * 4 + 0] + sred[r * 4 + 1]) + (sred[r * 4 + 2] + sred[r * 4 + 3]);
        float inv = 1.0f / S;
        if (act) {
            float4 o = make_float4(acc[r][0] * inv, acc[r][1] * inv,
                                   acc[r][2] * inv, acc[r][3] * inv);
            ((float4*)(base + (size_t)(i0 + r) * ROWSTR))[t] = o;
        }
    }
}

extern "C" void kernel_launch(void* const* d_in, const int* in_sizes, int n_in,
                              void* d_out, int out_size, void* d_ws, size_t ws_size,
                              hipStream_t stream) {
    (void)in_sizes; (void)n_in; (void)out_size; (void)d_ws; (void)ws_size;
    const int*   x     = (const int*)d_in[0];
    const int*   ei    = (const int*)d_in[1];
    const float* emb   = (const float*)d_in[2];
    const float* Wl    = (const float*)d_in[3];
    const float* bl    = (const float*)d_in[4];
    const float* Wr    = (const float*)d_in[5];
    const float* Wlast = (const float*)d_in[6];
    const float* blast = (const float*)d_in[7];
    float* base = (float*)d_out;
    const int* src = ei;             // edge_index[0]
    const int* dst = ei + N_EDGES;   // edge_index[1]

    k_embed<<<dim3(N_NODES), dim3(HID), 0, stream>>>(base, x, emb);
    for (int l = 0; l < 3; ++l) {
        k_scatter<<<dim3((int)(((long long)N_EDGES * 32 + 255) / 256)), dim3(256), 0, stream>>>(
            base, src, dst);
        k_transform<<<dim3(N_NODES / TNB), dim3(HID), 0, stream>>>(
            base, Wl + (size_t)l * HID * HID, bl + (size_t)l * HID, Wr + (size_t)l * HID * HID);
    }
    k_final<<<dim3(N_NODES / FNB), dim3(256), 0, stream>>>(base, Wlast, blast);
}

// Round 2
// 2198.282 us; speedup vs baseline: 4.6474x; 4.6474x over previous
//
#include <hip/hip_runtime.h>
#include <math.h>

#define N_NODES 100000
#define N_EDGES 1600000
#define HID 128
#define VOCAB 1000
#define ROWSTR 1000   // floats per output row; also per-node scratch slot

// per-node scratch layout inside its own d_out row (floats 0..999):
//   [0..127]   h buffer A
//   [128..255] h buffer B
//   [256..767] CSR col storage: 512 ints/row, rows 0..3124 hold all 1.6M edges
//   [768] cnt (int)  [769] row_ptr (int)  [770] cursor (int)
//   [771] chunk sum  [772] chunk offset   (rows 0..97 only, for the scan)
#define OFF_H0   0
#define OFF_H1   128
#define OFF_COL  256
#define OFF_CNT  768
#define OFF_PTR  769
#define OFF_CUR  770
#define OFF_CSUM 771
#define OFF_COFF 772

#define TNB 8    // nodes per layer block
#define FNB 4    // nodes per final block
#define CHUNK 1024
#define NBLK  98  // ceil(100000/1024)

__device__ __forceinline__ int* meta(float* b, int i, int off) {
    return (int*)(b + (size_t)i * ROWSTR + off);
}
__device__ __forceinline__ int* colp(float* b, int pos) {
    return (int*)(b + (size_t)(pos >> 9) * ROWSTR + OFF_COL + (pos & 511));
}

// h0[i] = emb[x[i]]; cnt = 0
__global__ __launch_bounds__(HID) void k_embed(float* __restrict__ base,
                                               const int* __restrict__ x,
                                               const float* __restrict__ emb) {
    int i = blockIdx.x, j = threadIdx.x;
    base[(size_t)i * ROWSTR + OFF_H0 + j] = emb[x[i] * HID + j];
    if (j == 0) *meta(base, i, OFF_CNT) = 0;
}

// cnt[dst]++
__global__ __launch_bounds__(256) void k_hist(float* __restrict__ base,
                                              const int* __restrict__ dst) {
    int e = blockIdx.x * 256 + threadIdx.x;
    if (e < N_EDGES) atomicAdd(meta(base, dst[e], OFF_CNT), 1);
}

// chunkSum[b] = sum of cnt over chunk b
__global__ __launch_bounds__(256) void k_chunk_sums(float* __restrict__ base) {
    int b = blockIdx.x, t = threadIdx.x;
    int s = 0;
    #pragma unroll
    for (int u = 0; u < 4; ++u) {
        int i = b * CHUNK + t * 4 + u;
        if (i < N_NODES) s += *meta(base, i, OFF_CNT);
    }
    #pragma unroll
    for (int o = 32; o > 0; o >>= 1) s += __shfl_xor(s, o, 64);
    __shared__ int ws[4];
    int wave = t >> 6, lane = t & 63;
    if (lane == 0) ws[wave] = s;
    __syncthreads();
    if (t == 0) *meta(base, b, OFF_CSUM) = ws[0] + ws[1] + ws[2] + ws[3];
}

// serial exclusive scan of 98 chunk sums (tiny)
__global__ void k_scan_top(float* __restrict__ base) {
    if (threadIdx.x == 0) {
        int run = 0;
        for (int b = 0; b < NBLK; ++b) {
            int v = *meta(base, b, OFF_CSUM);
            *meta(base, b, OFF_COFF) = run;
            run += v;
        }
    }
}

// row_ptr / cursor = global exclusive prefix of cnt
__global__ __launch_bounds__(256) void k_scan_apply(float* __restrict__ base) {
    int b = blockIdx.x, t = threadIdx.x;
    int c[4];
    #pragma unroll
    for (int u = 0; u < 4; ++u) {
        int i = b * CHUNK + t * 4 + u;
        c[u] = (i < N_NODES) ? *meta(base, i, OFF_CNT) : 0;
    }
    int tsum = c[0] + c[1] + c[2] + c[3];
    __shared__ int sc[256];
    sc[t] = tsum;
    __syncthreads();
    for (int o = 1; o < 256; o <<= 1) {
        int v = (t >= o) ? sc[t - o] : 0;
        __syncthreads();
        sc[t] += v;
        __syncthreads();
    }
    int start = *meta(base, b, OFF_COFF) + (sc[t] - tsum);
    #pragma unroll
    for (int u = 0; u < 4; ++u) {
        int i = b * CHUNK + t * 4 + u;
        if (i < N_NODES) {
            *meta(base, i, OFF_PTR) = start;
            *meta(base, i, OFF_CUR) = start;
            start += c[u];
        }
    }
}

// col[cursor[dst]++] = src
__global__ __launch_bounds__(256) void k_build(float* __restrict__ base,
                                               const int* __restrict__ src,
                                               const int* __restrict__ dst) {
    int e = blockIdx.x * 256 + threadIdx.x;
    if (e >= N_EDGES) return;
    int pos = atomicAdd(meta(base, dst[e], OFF_CUR), 1);
    *colp(base, pos) = src[e];
}

// fused: mean-gather + h_out = relu(mean@Wl + bl + h_in@Wr)
__global__ __launch_bounds__(HID) void k_layer(float* __restrict__ base,
                                               const float* __restrict__ Wl,
                                               const float* __restrict__ bl,
                                               const float* __restrict__ Wr,
                                               int in_off, int out_off) {
    int j = threadIdx.x;
    int i0 = blockIdx.x * TNB;
    __shared__ __align__(16) float s_m[TNB][HID];
    __shared__ __align__(16) float s_h[TNB][HID];

    for (int r = 0; r < TNB; ++r) {
        int i = i0 + r;
        int beg = *meta(base, i, OFF_PTR);
        int c   = *meta(base, i, OFF_CNT);
        float a = 0.f;
        for (int e = beg; e < beg + c; ++e) {
            int s = *colp(base, e);
            a += base[(size_t)s * ROWSTR + in_off + j];
        }
        s_m[r][j] = a / fmaxf((float)c, 1.0f);
        s_h[r][j] = base[(size_t)i * ROWSTR + in_off + j];
    }
    __syncthreads();

    float acc[TNB];
    #pragma unroll
    for (int r = 0; r < TNB; ++r) acc[r] = 0.f;

    for (int k4 = 0; k4 < HID / 4; ++k4) {
        int k = 4 * k4;
        float wl0 = Wl[(k + 0) * HID + j];
        float wl1 = Wl[(k + 1) * HID + j];
        float wl2 = Wl[(k + 2) * HID + j];
        float wl3 = Wl[(k + 3) * HID + j];
        float wr0 = Wr[(k + 0) * HID + j];
        float wr1 = Wr[(k + 1) * HID + j];
        float wr2 = Wr[(k + 2) * HID + j];
        float wr3 = Wr[(k + 3) * HID + j];
        #pragma unroll
        for (int r = 0; r < TNB; ++r) {
            float4 mv = ((const float4*)s_m[r])[k4];
            float4 hv = ((const float4*)s_h[r])[k4];
            acc[r] += mv.x * wl0 + mv.y * wl1 + mv.z * wl2 + mv.w * wl3
                    + hv.x * wr0 + hv.y * wr1 + hv.z * wr2 + hv.w * wr3;
        }
    }

    float bb = bl[j];
    #pragma unroll
    for (int r = 0; r < TNB; ++r)
        base[(size_t)(i0 + r) * ROWSTR + out_off + j] = fmaxf(acc[r] + bb, 0.f);
}

// out[i] = softmax(h[i] @ Wlast + blast), overwriting the full rows
__global__ __launch_bounds__(256) void k_final(float* __restrict__ base,
                                               const float* __restrict__ Wlast,
                                               const float* __restrict__ blast,
                                               int h_off) {
    int t = threadIdx.x;
    int i0 = blockIdx.x * FNB;
    __shared__ __align__(16) float sh[FNB][HID];
    __shared__ float sred[FNB * 4];

    for (int u = t; u < FNB * HID; u += 256) {
        int r = u >> 7, k = u & 127;
        sh[r][k] = base[(size_t)(i0 + r) * ROWSTR + h_off + k];
    }
    __syncthreads();

    const bool act = (t < 250);
    float acc[FNB][4];
    #pragma unroll
    for (int r = 0; r < FNB; ++r)
        #pragma unroll
        for (int c = 0; c < 4; ++c) acc[r][c] = 0.f;

    if (act) {
        const float4* wp = (const float4*)Wlast + t;
        for (int k4 = 0; k4 < HID / 4; ++k4) {
            int k = 4 * k4;
            float4 w0 = wp[(k + 0) * 250];
            float4 w1 = wp[(k + 1) * 250];
            float4 w2 = wp[(k + 2) * 250];
            float4 w3 = wp[(k + 3) * 250];
            #pragma unroll
            for (int r = 0; r < FNB; ++r) {
                float4 hv = ((const float4*)sh[r])[k4];
                acc[r][0] += hv.x * w0.x + hv.y * w1.x + hv.z * w2.x + hv.w * w3.x;
                acc[r][1] += hv.x * w0.y + hv.y * w1.y + hv.z * w2.y + hv.w * w3.y;
                acc[r][2] += hv.x * w0.z + hv.y * w1.z + hv.z * w2.z + hv.w * w3.z;
                acc[r][3] += hv.x * w0.w + hv.y * w1.w + hv.z * w2.w + hv.w * w3.w;
            }
        }
        float4 bb = ((const float4*)blast)[t];
        #pragma unroll
        for (int r = 0; r < FNB; ++r) {
            acc[r][0] += bb.x; acc[r][1] += bb.y; acc[r][2] += bb.z; acc[r][3] += bb.w;
        }
    }

    float lm[FNB];
    #pragma unroll
    for (int r = 0; r < FNB; ++r)
        lm[r] = act ? fmaxf(fmaxf(acc[r][0], acc[r][1]), fmaxf(acc[r][2], acc[r][3]))
                    : -INFINITY;
    #pragma unroll
    for (int s = 32; s > 0; s >>= 1)
        #pragma unroll
        for (int r = 0; r < FNB; ++r)
            lm[r] = fmaxf(lm[r], __shfl_xor(lm[r], s, 64));
    int wave = t >> 6, lane = t & 63;
    if (lane == 0) {
        #pragma unroll
        for (int r = 0; r < FNB; ++r) sred[r * 4 + wave] = lm[r];
    }
    __syncthreads();
    float M[FNB];
    #pragma unroll
    for (int r = 0; r < FNB; ++r)
        M[r] = fmaxf(fmaxf(sred[r * 4 + 0], sred[r * 4 + 1]),
                     fmaxf(sred[r * 4 + 2], sred[r * 4 + 3]));
    __syncthreads();

    float ls[FNB];
    #pragma unroll
    for (int r = 0; r < FNB; ++r) {
        if (act) {
            acc[r][0] = expf(acc[r][0] - M[r]);
            acc[r][1] = expf(acc[r][1] - M[r]);
            acc[r][2] = expf(acc[r][2] - M[r]);
            acc[r][3] = expf(acc[r][3] - M[r]);
            ls[r] = (acc[r][0] + acc[r][1]) + (acc[r][2] + acc[r][3]);
        } else {
            ls[r] = 0.f;
        }
    }
    #pragma unroll
    for (int s = 32; s > 0; s >>= 1)
        #pragma unroll
        for (int r = 0; r < FNB; ++r)
            ls[r] += __shfl_xor(ls[r], s, 64);
    if (lane == 0) {
        #pragma unroll
        for (int r = 0; r < FNB; ++r) sred[r * 4 + wave] = ls[r];
    }
    __syncthreads();

    #pragma unroll
    for (int r = 0; r < FNB; ++r) {
        float S = (sred[r * 4 + 0] + sred[r * 4 + 1]) + (sred[r * 4 + 2] + sred[r * 4 + 3]);
        float inv = 1.0f / S;
        if (act) {
            float4 o = make_float4(acc[r][0] * inv, acc[r][1] * inv,
                                   acc[r][2] * inv, acc[r][3] * inv);
            ((float4*)(base + (size_t)(i0 + r) * ROWSTR))[t] = o;
        }
    }
}

extern "C" void kernel_launch(void* const* d_in, const int* in_sizes, int n_in,
                              void* d_out, int out_size, void* d_ws, size_t ws_size,
                              hipStream_t stream) {
    (void)in_sizes; (void)n_in; (void)out_size; (void)d_ws; (void)ws_size;
    const int*   x     = (const int*)d_in[0];
    const int*   ei    = (const int*)d_in[1];
    const float* emb   = (const float*)d_in[2];
    const float* Wl    = (const float*)d_in[3];
    const float* bl    = (const float*)d_in[4];
    const float* Wr    = (const float*)d_in[5];
    const float* Wlast = (const float*)d_in[6];
    const float* blast = (const float*)d_in[7];
    float* base = (float*)d_out;
    const int* src = ei;
    const int* dst = ei + N_EDGES;

    const int EG = (N_EDGES + 255) / 256;

    k_embed<<<dim3(N_NODES), dim3(HID), 0, stream>>>(base, x, emb);
    k_hist<<<dim3(EG), dim3(256), 0, stream>>>(base, dst);
    k_chunk_sums<<<dim3(NBLK), dim3(256), 0, stream>>>(base);
    k_scan_top<<<dim3(1), dim3(64), 0, stream>>>(base);
    k_scan_apply<<<dim3(NBLK), dim3(256), 0, stream>>>(base);
    k_build<<<dim3(EG), dim3(256), 0, stream>>>(base, src, dst);

    int in_off = OFF_H0, out_off = OFF_H1;
    for (int l = 0; l < 3; ++l) {
        k_layer<<<dim3(N_NODES / TNB), dim3(HID), 0, stream>>>(
            base, Wl + (size_t)l * HID * HID, bl + (size_t)l * HID,
            Wr + (size_t)l * HID * HID, in_off, out_off);
        int tmp = in_off; in_off = out_off; out_off = tmp;
    }
    // after 3 layers h lives at in_off (== OFF_H1)
    k_final<<<dim3(N_NODES / FNB), dim3(256), 0, stream>>>(base, Wlast, blast, in_off);
}